// Round 1
// baseline (70.458 us; speedup 1.0000x reference)
//
#include <hip/hip_runtime.h>

#define E_EDGES 8192
#define KN 32
#define DD 128
#define HH 64

typedef __attribute__((ext_vector_type(8))) __bf16 bf16x8;
typedef __attribute__((ext_vector_type(4))) float f32x4;

__device__ __forceinline__ unsigned short f2bf(float f) {
    unsigned int u = __builtin_bit_cast(unsigned int, f);
    u += 0x7FFFu + ((u >> 16) & 1u);   // round-to-nearest-even
    return (unsigned short)(u >> 16);
}

__global__ __launch_bounds__(256)
void he_attn_kernel(const float* __restrict__ X,
                    const int* __restrict__ idx,
                    const float* __restrict__ W1,
                    const float* __restrict__ b1,
                    const float* __restrict__ W2,
                    const float* __restrict__ b2,
                    float* __restrict__ Zout,
                    float* __restrict__ Bout)
{
    const int e   = blockIdx.x;
    const int tid = threadIdx.x;
    const int lane = tid & 63;
    const int wv   = tid >> 6;       // wave 0..3

    __shared__ float xs32[KN][DD];                 // 16 KB f32 copy of x_he (for z-phase)
    __shared__ unsigned short xsb[KN][DD + 8];     // 8.7 KB bf16 x_he (padded rows, 272 B stride)
    __shared__ unsigned short wsb[HH][DD + 8];     // 17.4 KB bf16 W1[e]
    __shared__ float wpart[4][KN];                 // per-wave partial w[k]
    __shared__ float beta_s[KN];

    // ---- stage x_he (gather 32 rows x 128 f32), keep f32 + bf16 copies ----
    #pragma unroll
    for (int it = 0; it < 4; ++it) {
        int i = tid + it * 256;
        int k = i >> 5;          // 32 float4-chunks per row
        int c = i & 31;
        int row = idx[e * KN + k];
        float4 v = reinterpret_cast<const float4*>(X)[(size_t)row * (DD / 4) + c];
        *reinterpret_cast<float4*>(&xs32[k][c * 4]) = v;
        ushort4 bv;
        bv.x = f2bf(v.x); bv.y = f2bf(v.y); bv.z = f2bf(v.z); bv.w = f2bf(v.w);
        *reinterpret_cast<ushort4*>(&xsb[k][c * 4]) = bv;
    }
    // ---- stage W1[e] (64 x 128 f32, contiguous) as bf16 ----
    const float4* W1e = reinterpret_cast<const float4*>(W1 + (size_t)e * HH * DD);
    #pragma unroll
    for (int it = 0; it < 8; ++it) {
        int i = tid + it * 256;
        int jj = i >> 5;
        int c  = i & 31;
        float4 v = W1e[i];
        ushort4 bv;
        bv.x = f2bf(v.x); bv.y = f2bf(v.y); bv.z = f2bf(v.z); bv.w = f2bf(v.w);
        *reinterpret_cast<ushort4*>(&wsb[jj][c * 4]) = bv;
    }
    __syncthreads();

    // ---- h-GEMM: h[32x64] = x_he[32x128] . W1[e]^T, bf16 MFMA, f32 accum ----
    // wave wv owns j in [16*wv, 16*wv+16); both M-tiles (k 0..15, 16..31)
    const int cl = lane & 15;    // column within 16-wide tile
    const int kg = lane >> 4;    // k-chunk group 0..3
    f32x4 acc0 = {0.f, 0.f, 0.f, 0.f};
    f32x4 acc1 = {0.f, 0.f, 0.f, 0.f};
    #pragma unroll
    for (int kc = 0; kc < 4; ++kc) {
        const int ds = kc * 32 + kg * 8;
        bf16x8 a0 = *reinterpret_cast<const bf16x8*>(&xsb[cl][ds]);        // A rows 0..15
        bf16x8 a1 = *reinterpret_cast<const bf16x8*>(&xsb[16 + cl][ds]);   // A rows 16..31
        bf16x8 bb = *reinterpret_cast<const bf16x8*>(&wsb[wv * 16 + cl][ds]); // B cols (=W1 rows)
        acc0 = __builtin_amdgcn_mfma_f32_16x16x32_bf16(a0, bb, acc0, 0, 0, 0);
        acc1 = __builtin_amdgcn_mfma_f32_16x16x32_bf16(a1, bb, acc1, 0, 0, 0);
    }

    // ---- epilogue: h = leaky(acc + b1[j]); partial w[k] += h * W2[j] ----
    // D layout: col j = wv*16 + (lane&15), row k = mt*16 + (lane>>4)*4 + reg   [m89]
    const int j = wv * 16 + cl;
    const float b1j = b1[e * HH + j];
    const float w2j = W2[e * HH + j];
    float pk[8];
    #pragma unroll
    for (int r = 0; r < 4; ++r) {
        float h0 = acc0[r] + b1j; h0 = (h0 > 0.f) ? h0 : 0.01f * h0;
        float h1 = acc1[r] + b1j; h1 = (h1 > 0.f) ? h1 : 0.01f * h1;
        pk[r]     = h0 * w2j;
        pk[4 + r] = h1 * w2j;
    }
    // reduce over the 16 lanes sharing (lane>>4)  (the 16 j's of this wave)
    #pragma unroll
    for (int m = 1; m < 16; m <<= 1) {
        #pragma unroll
        for (int q = 0; q < 8; ++q) pk[q] += __shfl_xor(pk[q], m);
    }
    if (cl == 0) {
        #pragma unroll
        for (int r = 0; r < 4; ++r) {
            wpart[wv][kg * 4 + r]      = pk[r];
            wpart[wv][16 + kg * 4 + r] = pk[4 + r];
        }
    }
    __syncthreads();

    // ---- softmax over K=32 (lanes 0..31 of wave 0) ----
    if (tid < KN) {
        float v = b2[e] + wpart[0][tid] + wpart[1][tid] + wpart[2][tid] + wpart[3][tid];
        float mx = v;
        #pragma unroll
        for (int off = 16; off >= 1; off >>= 1) mx = fmaxf(mx, __shfl_xor(mx, off));
        float ex = __expf(v - mx);
        float s = ex;
        #pragma unroll
        for (int off = 16; off >= 1; off >>= 1) s += __shfl_xor(s, off);
        float beta = ex / s;
        beta_s[tid] = beta;
        Bout[(size_t)e * KN + tid] = beta;
    }
    __syncthreads();

    // ---- z[d] = sum_k beta[k] * x_he[k][d] (f32), Z = tanh(leaky(z)) ----
    if (tid < DD) {
        float z = 0.f;
        #pragma unroll
        for (int k = 0; k < KN; ++k) z += beta_s[k] * xs32[k][tid];
        z = (z > 0.f) ? z : 0.01f * z;
        Zout[(size_t)e * DD + tid] = tanhf(z);
    }
}

extern "C" void kernel_launch(void* const* d_in, const int* in_sizes, int n_in,
                              void* d_out, int out_size, void* d_ws, size_t ws_size,
                              hipStream_t stream) {
    const float* X   = (const float*)d_in[0];
    const int*   idx = (const int*)d_in[1];
    const float* W1  = (const float*)d_in[2];
    const float* b1  = (const float*)d_in[3];
    const float* W2  = (const float*)d_in[4];
    const float* b2  = (const float*)d_in[5];
    float* Zout = (float*)d_out;                       // [E, D]
    float* Bout = Zout + (size_t)E_EDGES * DD;         // [E, K]
    (void)in_sizes; (void)n_in; (void)out_size; (void)d_ws; (void)ws_size;
    he_attn_kernel<<<dim3(E_EDGES), dim3(256), 0, stream>>>(X, idx, W1, b1, W2, b2, Zout, Bout);
}

// Round 2
// 64.943 us; speedup vs baseline: 1.0849x; 1.0849x over previous
//
#include <hip/hip_runtime.h>

#define E_EDGES 8192
#define KN 32
#define DD 128
#define HH 64
#define XPAD 8   // bf16 row padding: row stride 272 B

typedef __attribute__((ext_vector_type(8))) __bf16 bf16x8;
typedef __attribute__((ext_vector_type(8))) unsigned short u16x8;
typedef __attribute__((ext_vector_type(4))) float f32x4;

__device__ __forceinline__ unsigned short f2bf(float f) {
    unsigned int u = __builtin_bit_cast(unsigned int, f);
    u += 0x7FFFu + ((u >> 16) & 1u);   // round-to-nearest-even
    return (unsigned short)(u >> 16);
}

__device__ __forceinline__ bf16x8 pack_bf8(float4 a, float4 b) {
    u16x8 u;
    u[0] = f2bf(a.x); u[1] = f2bf(a.y); u[2] = f2bf(a.z); u[3] = f2bf(a.w);
    u[4] = f2bf(b.x); u[5] = f2bf(b.y); u[6] = f2bf(b.z); u[7] = f2bf(b.w);
    return __builtin_bit_cast(bf16x8, u);
}

__global__ __launch_bounds__(256, 4)
void he_attn_kernel(const float* __restrict__ X,
                    const int* __restrict__ idx,
                    const float* __restrict__ W1,
                    const float* __restrict__ b1,
                    const float* __restrict__ W2,
                    const float* __restrict__ b2,
                    float* __restrict__ Zout,
                    float* __restrict__ Bout)
{
    const int e    = blockIdx.x;
    const int tid  = threadIdx.x;
    const int lane = tid & 63;
    const int wv   = tid >> 6;       // wave 0..3
    const int cl   = lane & 15;      // column within 16-wide tile
    const int kg   = lane >> 4;      // k-chunk group 0..3

    __shared__ unsigned short xsb[KN][DD + XPAD];  // 8.5 KB bf16 x_he
    __shared__ float wpart[4][KN];                 // per-wave partial w[k]
    __shared__ float beta_s[KN];

    // ---- W1 B-fragments: DIRECT global->reg (each row read exactly once,
    //      no reuse -> LDS staging would be pure overhead). Issue all 8
    //      float4 loads up front so they overlap the x-gather below. ----
    const int j = wv * 16 + cl;                    // W1 row this lane feeds
    const float* W1r = W1 + ((size_t)e * HH + j) * DD;
    float4 wf[8];
    #pragma unroll
    for (int kc = 0; kc < 4; ++kc) {
        wf[2 * kc]     = *reinterpret_cast<const float4*>(W1r + kc * 32 + kg * 8);
        wf[2 * kc + 1] = *reinterpret_cast<const float4*>(W1r + kc * 32 + kg * 8 + 4);
    }

    // ---- stage x_he (gather 32 rows x 128 f32) as bf16 into LDS ----
    #pragma unroll
    for (int it = 0; it < 4; ++it) {
        int i = tid + it * 256;
        int k = i >> 5;          // 32 float4-chunks per row
        int c = i & 31;
        int row = idx[e * KN + k];
        float4 v = reinterpret_cast<const float4*>(X)[(size_t)row * (DD / 4) + c];
        ushort4 bv;
        bv.x = f2bf(v.x); bv.y = f2bf(v.y); bv.z = f2bf(v.z); bv.w = f2bf(v.w);
        *reinterpret_cast<ushort4*>(&xsb[k][c * 4]) = bv;
    }
    __syncthreads();

    // ---- h-GEMM: h[32x64] = x_he[32x128] . W1[e]^T, bf16 MFMA, f32 accum ----
    f32x4 acc0 = {0.f, 0.f, 0.f, 0.f};
    f32x4 acc1 = {0.f, 0.f, 0.f, 0.f};
    #pragma unroll
    for (int kc = 0; kc < 4; ++kc) {
        const int ds = kc * 32 + kg * 8;
        bf16x8 a0 = *reinterpret_cast<const bf16x8*>(&xsb[cl][ds]);        // A rows 0..15
        bf16x8 a1 = *reinterpret_cast<const bf16x8*>(&xsb[16 + cl][ds]);   // A rows 16..31
        bf16x8 bb = pack_bf8(wf[2 * kc], wf[2 * kc + 1]);                  // B from regs
        acc0 = __builtin_amdgcn_mfma_f32_16x16x32_bf16(a0, bb, acc0, 0, 0, 0);
        acc1 = __builtin_amdgcn_mfma_f32_16x16x32_bf16(a1, bb, acc1, 0, 0, 0);
    }

    // ---- epilogue: h = leaky(acc + b1[j]); partial w[k] += h * W2[j] ----
    // D layout: col j = wv*16 + (lane&15), row k = mt*16 + (lane>>4)*4 + reg   [m89]
    const float b1j = b1[e * HH + j];
    const float w2j = W2[e * HH + j];
    float pk[8];
    #pragma unroll
    for (int r = 0; r < 4; ++r) {
        float h0 = acc0[r] + b1j; h0 = (h0 > 0.f) ? h0 : 0.01f * h0;
        float h1 = acc1[r] + b1j; h1 = (h1 > 0.f) ? h1 : 0.01f * h1;
        pk[r]     = h0 * w2j;
        pk[4 + r] = h1 * w2j;
    }
    // reduce over the 16 lanes sharing (lane>>4)  (the 16 j's of this wave)
    #pragma unroll
    for (int m = 1; m < 16; m <<= 1) {
        #pragma unroll
        for (int q = 0; q < 8; ++q) pk[q] += __shfl_xor(pk[q], m);
    }
    if (cl == 0) {
        #pragma unroll
        for (int r = 0; r < 4; ++r) {
            wpart[wv][kg * 4 + r]      = pk[r];
            wpart[wv][16 + kg * 4 + r] = pk[4 + r];
        }
    }
    __syncthreads();

    // ---- softmax over K=32 (lanes 0..31 of wave 0) ----
    if (tid < KN) {
        float v = b2[e] + wpart[0][tid] + wpart[1][tid] + wpart[2][tid] + wpart[3][tid];
        float mx = v;
        #pragma unroll
        for (int off = 16; off >= 1; off >>= 1) mx = fmaxf(mx, __shfl_xor(mx, off));
        float ex = __expf(v - mx);
        float s = ex;
        #pragma unroll
        for (int off = 16; off >= 1; off >>= 1) s += __shfl_xor(s, off);
        float beta = ex / s;
        beta_s[tid] = beta;
        Bout[(size_t)e * KN + tid] = beta;
    }
    __syncthreads();

    // ---- z[d] = sum_k beta[k] * x_he[k][d] (bf16 x, exact f32 accum),
    //      Z = tanh(leaky(z)) ----
    if (tid < DD) {
        float z = 0.f;
        #pragma unroll
        for (int k = 0; k < KN; ++k) {
            unsigned int b = xsb[k][tid];
            float xv = __builtin_bit_cast(float, b << 16);   // bf16->f32 exact
            z += beta_s[k] * xv;
        }
        z = (z > 0.f) ? z : 0.01f * z;
        Zout[(size_t)e * DD + tid] = tanhf(z);
    }
}

extern "C" void kernel_launch(void* const* d_in, const int* in_sizes, int n_in,
                              void* d_out, int out_size, void* d_ws, size_t ws_size,
                              hipStream_t stream) {
    const float* X   = (const float*)d_in[0];
    const int*   idx = (const int*)d_in[1];
    const float* W1  = (const float*)d_in[2];
    const float* b1  = (const float*)d_in[3];
    const float* W2  = (const float*)d_in[4];
    const float* b2  = (const float*)d_in[5];
    float* Zout = (float*)d_out;                       // [E, D]
    float* Bout = Zout + (size_t)E_EDGES * DD;         // [E, K]
    (void)in_sizes; (void)n_in; (void)out_size; (void)d_ws; (void)ws_size;
    he_attn_kernel<<<dim3(E_EDGES), dim3(256), 0, stream>>>(X, idx, W1, b1, W2, b2, Zout, Bout);
}